// Round 6
// baseline (291.782 us; speedup 1.0000x reference)
//
#include <hip/hip_runtime.h>

#define BB 32
#define PP 32768
#define CC 81
#define RPB 64                      // rows per tile
#define TPB 256                     // 4 threads per row
#define NT 16                       // tiles per block
#define GRID ((BB * PP) / (RPB * NT))   // 1024 blocks = 4/CU, all co-resident

// ws layout (bytes):
//   0:    int done1            (K1 block-completion counter)
//   4:    int flag             (1 = all rows fast-path, K1 wrote out[1])
//   8:    int done2            (mine block-completion counter)
//   16:   ull g_sce            (bit-cast double: positive-CE total, stash)
//   24:   ull g_N              (bit-cast double: num_pos total, stash)
//   32:   double neg_acc
//   40:   double d_ll[32]
//   296:  double d_ce[32]
//   552:  double d_msum[32]
//   808:  int    num_pos[32]
//   936:  int    nnz[32]
//   2048: float  mine[B*P]  (4 MB)

__device__ __forceinline__ float sl1f(float d) {
    float ad = fabsf(d);
    return ad < 1.f ? 0.5f * d * d : ad - 0.5f;
}

#define EXP4(w) { w.x = __expf(w.x); w.y = __expf(w.y); w.z = __expf(w.z); w.w = __expf(w.w); }

// Issue order matters: scalars (labels/loc) FIRST, then conf float4s, so the
// deposit-phase vmcnt wait on a conf set never has younger scalar loads forcing
// a full drain of the other in-flight set.
#define PREFETCH(SET, IT1) { \
    const size_t gpn = row0 + (size_t)(IT1) * RPB + r; \
    lab##SET = labels[gpn]; la##SET = locd[gpn * 4 + q]; lb##SET = loct[gpn * 4 + q]; \
    const float4* sp = (const float4*)(conf + (row0 + (size_t)(IT1) * RPB) * CC); \
    v##SET##0 = sp[t];        v##SET##1 = sp[t + 256]; v##SET##2 = sp[t + 512]; \
    v##SET##3 = sp[t + 768];  v##SET##4 = sp[t + 1024]; \
    if (t < 16) v##SET##t = sp[1280 + t]; }

#define DEPOSIT(SET) { \
    float4* dx = (float4*)ex; float4 w; \
    w = v##SET##0; EXP4(w); dx[t]        = w; \
    w = v##SET##1; EXP4(w); dx[t + 256]  = w; \
    w = v##SET##2; EXP4(w); dx[t + 512]  = w; \
    w = v##SET##3; EXP4(w); dx[t + 768]  = w; \
    w = v##SET##4; EXP4(w); dx[t + 1024] = w; \
    if (t < 16) { w = v##SET##t; EXP4(w); dx[1280 + t] = w; } }

#define REDUCE(SET, IT) { \
    const size_t gp = row0 + (size_t)(IT) * RPB + r; \
    const bool pos = lab##SET > 0; \
    const float* rowp = ex + r * CC; \
    float s0 = 0.f, s1 = 0.f; \
    _Pragma("unroll") \
    for (int c = 0; c < 10; ++c) { s0 += rowp[q + 8 * c]; s1 += rowp[q + 8 * c + 4]; } \
    float s = s0 + s1; \
    if (q == 0) s += rowp[80]; \
    float ll = pos ? sl1f(la##SET - lb##SET) : 0.f; \
    s += __shfl_xor(s, 1);  ll += __shfl_xor(ll, 1); \
    s += __shfl_xor(s, 2);  ll += __shfl_xor(ll, 2); \
    if (q == 0) { \
        const float exl = rowp[lab##SET]; \
        const float ce = __logf(__fdividef(s, exl)); \
        a_ll += ll; \
        float mv = 0.f; \
        if (pos) { a_pce += ce; a_pc += 1.f; } \
        else { mv = fmaxf(ce, 0.f); a_mv += mv; a_nz += (mv > 0.f) ? 1.f : 0.f; } \
        mine[gp] = mv; \
    } }

__global__ __launch_bounds__(TPB, 4) void ce_loc_kernel(
    const float* __restrict__ conf, const int* __restrict__ labels,
    const float* __restrict__ locd, const float* __restrict__ loct,
    char* __restrict__ wsb, float* __restrict__ out)
{
    int*    done1   = (int*)wsb;
    int*    flag    = (int*)(wsb + 4);
    unsigned long long* g_sce = (unsigned long long*)(wsb + 16);
    unsigned long long* g_N   = (unsigned long long*)(wsb + 24);
    double* d_ll    = (double*)(wsb + 40);
    double* d_ce    = (double*)(wsb + 296);
    double* d_msum  = (double*)(wsb + 552);
    int*    num_pos = (int*)(wsb + 808);
    int*    nnz     = (int*)(wsb + 936);
    float*  mine    = (float*)(wsb + 2048);

    __shared__ float ex[RPB * CC];          // 20736 B
    __shared__ float part[4][5];
    __shared__ int lastblk;

    const int t = threadIdx.x;
    const int r = t >> 2, q = t & 3;
    const size_t row0 = (size_t)blockIdx.x * (RPB * NT);
    const int b = blockIdx.x >> 5;          // 32 blocks per batch row

    int labA, labB; float laA, lbA, laB, lbB;
    float4 vA0, vA1, vA2, vA3, vA4, vAt;
    float4 vB0, vB1, vB2, vB3, vB4, vBt;

    PREFETCH(A, 0)                          // prologue

    float a_ll = 0.f, a_pce = 0.f, a_pc = 0.f, a_mv = 0.f, a_nz = 0.f;

    for (int itp = 0; itp < NT / 2; ++itp) {
        __syncthreads();                    // ex consumed
        PREFETCH(B, 2 * itp + 1)            // B in flight across A's deposit+reduce
        DEPOSIT(A)                          // waits only on A's conf loads
        __syncthreads();
        REDUCE(A, 2 * itp)                  // labA/laA/lbA already in regs: no wait
        __syncthreads();
        if (itp < NT / 2 - 1) PREFETCH(A, 2 * itp + 2)
        DEPOSIT(B)
        __syncthreads();
        REDUCE(B, 2 * itp + 1)
    }

    // ---- per-block reduce + 5 atomics ----
#pragma unroll
    for (int off = 32; off; off >>= 1) {
        a_ll  += __shfl_down(a_ll, off);
        a_pce += __shfl_down(a_pce, off);
        a_pc  += __shfl_down(a_pc, off);
        a_mv  += __shfl_down(a_mv, off);
        a_nz  += __shfl_down(a_nz, off);
    }
    const int wv = t >> 6;
    if ((t & 63) == 0) {
        part[wv][0] = a_ll; part[wv][1] = a_pce; part[wv][2] = a_pc;
        part[wv][3] = a_mv; part[wv][4] = a_nz;
    }
    __syncthreads();
    if (t == 0) {
        float x0 = 0, x1 = 0, x2 = 0, x3 = 0, x4 = 0;
#pragma unroll
        for (int i = 0; i < 4; ++i) {
            x0 += part[i][0]; x1 += part[i][1]; x2 += part[i][2];
            x3 += part[i][3]; x4 += part[i][4];
        }
        atomicAdd(&d_ll[b], (double)x0);
        atomicAdd(&d_ce[b], (double)x1);
        atomicAdd(&num_pos[b], (int)x2);
        atomicAdd(&d_msum[b], (double)x3);
        atomicAdd(&nnz[b], (int)x4);
    }

    // ---- last-block fused finalize (device-scope handshake) ----
    __threadfence();
    if (t == 0) lastblk = (atomicAdd(done1, 1) == GRID - 1);
    __syncthreads();
    if (!lastblk) return;

    if (t < 64) {
        double ll = 0.0, ce = 0.0, msel = 0.0;
        int np = 0, fastf = 1;
        if (t < 32) {
            ll = atomicAdd(&d_ll[t], 0.0);       // device-scope coherent reads
            ce = atomicAdd(&d_ce[t], 0.0);
            const double ms = atomicAdd(&d_msum[t], 0.0);
            np = atomicAdd(&num_pos[t], 0);
            const int nz = atomicAdd(&nnz[t], 0);
            const int k = min(3 * np, PP - 1);
            if (k <= 0)       { fastf = 1; msel = 0.0; }
            else if (k >= nz) { fastf = 1; msel = ms; }
            else              { fastf = 0; msel = 0.0; }
        }
#pragma unroll
        for (int off = 32; off; off >>= 1) {
            ll   += __shfl_down(ll, off);
            ce   += __shfl_down(ce, off);
            msel += __shfl_down(msel, off);
            np   += __shfl_down(np, off);
            fastf = min(fastf, __shfl_down(fastf, off));
        }
        if (t == 0) {
            const double N = (double)np;
            out[0] = (float)(ll / N);                       // LOC_WEIGHT = 1
            atomicExch(g_sce, (unsigned long long)__double_as_longlong(ce));
            atomicExch(g_N,   (unsigned long long)__double_as_longlong(N));
            if (fastf) {
                out[1] = (float)((ce + msel) / N);          // CONF_WEIGHT = 1
                atomicExch(flag, 1);
            } else {
                atomicExch(flag, 2);                        // slow path: mine_kernel finalizes
            }
        }
    }
}

// Slow-path mining: per-row top-k sum via radix select on float bits (keys >= 0,
// uint-monotone). Fast rows take the msum shortcut. Last block finalizes out[1].
// When flag==1 (all rows fast), every block exits immediately.
__global__ __launch_bounds__(1024) void mine_kernel(
    char* __restrict__ wsb, float* __restrict__ out)
{
    int*    flag    = (int*)(wsb + 4);
    int*    done2   = (int*)(wsb + 8);
    unsigned long long* g_sce = (unsigned long long*)(wsb + 16);
    unsigned long long* g_N   = (unsigned long long*)(wsb + 24);
    double* neg_acc = (double*)(wsb + 32);
    double* d_msum  = (double*)(wsb + 552);
    int*    num_pos = (int*)(wsb + 808);
    int*    nnz     = (int*)(wsb + 936);
    const float* mine = (const float*)(wsb + 2048);

    const int b = blockIdx.x;
    const int t = threadIdx.x;

    __shared__ int sh_flag, sh_np, sh_nz;
    if (t == 0) {
        sh_flag = atomicAdd(flag, 0);
        sh_np = atomicAdd(&num_pos[b], 0);
        sh_nz = atomicAdd(&nnz[b], 0);
    }
    __syncthreads();
    if (sh_flag == 1) return;               // K1 already wrote out[1]

    const int k = min(3 * sh_np, PP - 1);
    if (k > 0) {
        if (k >= sh_nz) {                   // fast row: all nonzero values selected
            if (t == 0) atomicAdd(neg_acc, atomicAdd(&d_msum[b], 0.0));
        } else {
            const float* mr = mine + (size_t)b * PP;
            __shared__ unsigned hist[256];
            __shared__ unsigned sh_prefix;
            __shared__ int sh_remaining;
            __shared__ float sred[16];

            unsigned prefix = 0;
            int remaining = k;
            for (int lvl = 0; lvl < 4; ++lvl) {
                const int shift = 24 - lvl * 8;
                if (t < 256) hist[t] = 0;
                __syncthreads();
                for (int p = t; p < PP; p += 1024) {
                    const unsigned key = __float_as_uint(mr[p]);
                    const bool cand = (lvl == 0) || ((key >> (shift + 8)) == prefix);
                    const unsigned long long zb = __ballot(cand && key == 0u);
                    if ((t & 63) == 0 && zb) atomicAdd(&hist[0], (unsigned)__popcll(zb));
                    if (cand && key != 0u) atomicAdd(&hist[(key >> shift) & 255u], 1u);
                }
                __syncthreads();
                if (t == 0) {
                    unsigned c = 0;
                    int j = 255;
                    for (; j > 0; --j) {
                        const unsigned h = hist[j];
                        if (c + h >= (unsigned)remaining) break;
                        c += h;
                    }
                    sh_prefix = (prefix << 8) | (unsigned)j;
                    sh_remaining = remaining - (int)c;
                }
                __syncthreads();
                prefix = sh_prefix;
                remaining = sh_remaining;
                __syncthreads();
            }

            const unsigned vkey = prefix;
            const float v = __uint_as_float(vkey);
            float sgt = 0.f;
            for (int p = t; p < PP; p += 1024) {
                const float mv = mr[p];
                if (__float_as_uint(mv) > vkey) sgt += mv;
            }
#pragma unroll
            for (int off = 32; off; off >>= 1) sgt += __shfl_down(sgt, off);
            if ((t & 63) == 0) sred[t >> 6] = sgt;
            __syncthreads();
            if (t == 0) {
                float tot = 0.f;
#pragma unroll
                for (int w2 = 0; w2 < 16; ++w2) tot += sred[w2];
                tot += (float)remaining * v;     // boundary-value ties
                atomicAdd(neg_acc, (double)tot);
            }
        }
    }

    // every block (fast, slow, or k<=0) checks in exactly once
    __threadfence();
    if (t == 0) {
        if (atomicAdd(done2, 1) == BB - 1) {
            const double sce = __longlong_as_double((long long)atomicAdd(g_sce, 0ull));
            const double N   = __longlong_as_double((long long)atomicAdd(g_N, 0ull));
            const double na  = atomicAdd(neg_acc, 0.0);
            out[1] = (float)((sce + na) / N);
        }
    }
}

extern "C" void kernel_launch(void* const* d_in, const int* in_sizes, int n_in,
                              void* d_out, int out_size, void* d_ws, size_t ws_size,
                              hipStream_t stream)
{
    const float* locd   = (const float*)d_in[0];
    const float* conf   = (const float*)d_in[1];
    const float* loct   = (const float*)d_in[2];
    const int*   labels = (const int*)d_in[3];
    float* out = (float*)d_out;
    char* wsb = (char*)d_ws;

    hipMemsetAsync(d_ws, 0, 2048, stream);   // zero counters/accumulators (graph-safe)

    ce_loc_kernel<<<GRID, TPB, 0, stream>>>(conf, labels, locd, loct, wsb, out);
    mine_kernel<<<BB, 1024, 0, stream>>>(wsb, out);
}